// Round 1
// baseline (3648.029 us; speedup 1.0000x reference)
//
#include <hip/hip_runtime.h>
#include <math.h>

#define D_MODEL 2048
#define NUM_HEADS 16
#define HEAD_DIM 128
#define BB 2
#define TT 2048
#define QKV_N (D_MODEL + 2 * HEAD_DIM) /* 2304 */

// ---------------------------------------------------------------------------
// fp32 tiled GEMM: C[M,N] = A[M,K] @ B[K,N], all row-major.
// 64x64 tile, BK=16, 256 threads, 4x4 micro-tile per thread.
// M,N,K must be multiples of 64/64/16 (true here: 4096x2304x2048, 4096x2048x2048).
// ---------------------------------------------------------------------------
__global__ __launch_bounds__(256) void gemm_f32_64x64(
    const float* __restrict__ A, const float* __restrict__ B,
    float* __restrict__ C, int M, int N, int K)
{
  __shared__ float As[16][64]; // [k][m]
  __shared__ float Bs[16][64]; // [k][n]
  const int tid = threadIdx.x;
  const int tx = tid & 15;   // n direction
  const int ty = tid >> 4;   // m direction
  const int m0 = blockIdx.y * 64;
  const int n0 = blockIdx.x * 64;

  // A tile load: one float4 per thread: row = tid/4 (0..63), cols (tid%4)*4..+3
  const int a_row = tid >> 2;
  const int a_col = (tid & 3) << 2;
  // B tile load: one float4 per thread: row = tid/16 (0..15), cols (tid%16)*4..+3
  const int b_row = tid >> 4;
  const int b_col = (tid & 15) << 2;

  float acc[4][4] = {{0.f}};

  for (int k0 = 0; k0 < K; k0 += 16) {
    const float4 av = *(const float4*)&A[(size_t)(m0 + a_row) * K + k0 + a_col];
    const float4 bv = *(const float4*)&B[(size_t)(k0 + b_row) * N + n0 + b_col];
    __syncthreads(); // protect previous iteration's LDS reads
    As[a_col + 0][a_row] = av.x;
    As[a_col + 1][a_row] = av.y;
    As[a_col + 2][a_row] = av.z;
    As[a_col + 3][a_row] = av.w;
    *(float4*)&Bs[b_row][b_col] = bv;
    __syncthreads();
#pragma unroll
    for (int kk = 0; kk < 16; kk++) {
      float a[4], b[4];
#pragma unroll
      for (int i = 0; i < 4; i++) a[i] = As[kk][ty * 4 + i];
#pragma unroll
      for (int j = 0; j < 4; j++) b[j] = Bs[kk][tx * 4 + j];
#pragma unroll
      for (int i = 0; i < 4; i++)
#pragma unroll
        for (int j = 0; j < 4; j++) acc[i][j] += a[i] * b[j];
    }
  }

#pragma unroll
  for (int i = 0; i < 4; i++) {
    const int m = m0 + ty * 4 + i;
    float4 out;
    out.x = acc[i][0]; out.y = acc[i][1]; out.z = acc[i][2]; out.w = acc[i][3];
    *(float4*)&C[(size_t)m * N + n0 + tx * 4] = out;
  }
}

// ---------------------------------------------------------------------------
// RoPE in-place on qkv. Treat k as head index NUM_HEADS (its 128 cols start at
// D_MODEL = 16*128). One thread per (b,t,head,i) rotation pair, i in [0,64).
// ---------------------------------------------------------------------------
__global__ __launch_bounds__(256) void rope_kernel(
    float* __restrict__ qkv, const float* __restrict__ sin_t,
    const float* __restrict__ cos_t)
{
  const int idx = blockIdx.x * 256 + threadIdx.x;
  const int pairs_per_row = (NUM_HEADS + 1) * 64; // 1088
  const int total = BB * TT * pairs_per_row;
  if (idx >= total) return;
  const int p  = idx % pairs_per_row;
  const int bt = idx / pairs_per_row;
  const int t  = bt % TT;
  const int h  = p >> 6;   // 0..16 (16 == k)
  const int i  = p & 63;
  const float s = sin_t[t * 64 + i];
  const float c = cos_t[t * 64 + i];
  float* base = qkv + (size_t)bt * QKV_N + h * HEAD_DIM;
  const float x1 = base[i];
  const float x2 = base[64 + i];
  base[i]      = x1 * c - x2 * s;
  base[64 + i] = x2 * c + x1 * s;
}

// ---------------------------------------------------------------------------
// MQA attention, one block (128 threads = 2 waves) per (t, h, b).
// Scores for all s <= t live in LDS (2048 floats), then block softmax, then
// per-dim P@V accumulation with coalesced v reads.
// ---------------------------------------------------------------------------
__global__ __launch_bounds__(128) void attn_kernel(
    const float* __restrict__ qkv, const int* __restrict__ doc_ids,
    float* __restrict__ attn_out)
{
  const int t = blockIdx.x;
  const int h = blockIdx.y;
  const int b = blockIdx.z;
  const int tid = threadIdx.x;

  __shared__ __align__(16) float sc[TT];     // scores -> probs
  __shared__ __align__(16) float q_s[HEAD_DIM];
  __shared__ float wred[2];
  __shared__ float wred2[2];

  const float* qrow = qkv + (size_t)(b * TT + t) * QKV_N + h * HEAD_DIM;
  q_s[tid] = qrow[tid];
  __syncthreads();

  const int mydoc = doc_ids[b * TT + t];
  const float scale = 0.088388347648318440550f; // 1/sqrt(128)
  const float NEG = -1.0e30f;

  // ---- scores ----
  const float4* q4 = (const float4*)q_s;
  for (int s = tid; s <= t; s += 128) {
    float val = NEG;
    if (doc_ids[b * TT + s] == mydoc) {
      const float4* kr = (const float4*)(qkv + (size_t)(b * TT + s) * QKV_N + D_MODEL);
      float ax = 0.f, ay = 0.f, az = 0.f, aw = 0.f;
#pragma unroll
      for (int d = 0; d < HEAD_DIM / 4; d++) {
        const float4 kv = kr[d];
        const float4 qv = q4[d];
        ax += qv.x * kv.x; ay += qv.y * kv.y;
        az += qv.z * kv.z; aw += qv.w * kv.w;
      }
      val = (ax + ay + az + aw) * scale;
    }
    sc[s] = val;
  }
  __syncthreads();

  // ---- max reduce over s in [0, t] ----
  float m = NEG;
  for (int s = tid; s <= t; s += 128) m = fmaxf(m, sc[s]);
#pragma unroll
  for (int off = 32; off > 0; off >>= 1) m = fmaxf(m, __shfl_down(m, off));
  if ((tid & 63) == 0) wred[tid >> 6] = m;
  __syncthreads();
  m = fmaxf(wred[0], wred[1]);

  // ---- exp + sum ----
  float lsum = 0.f;
  for (int s = tid; s <= t; s += 128) {
    const float p = __expf(sc[s] - m);
    sc[s] = p;
    lsum += p;
  }
#pragma unroll
  for (int off = 32; off > 0; off >>= 1) lsum += __shfl_down(lsum, off);
  if ((tid & 63) == 0) wred2[tid >> 6] = lsum;
  __syncthreads();
  const float l = wred2[0] + wred2[1];
  __syncthreads(); // sc[] writes complete before everyone reads all of sc

  // ---- P @ V: thread tid owns output dim tid ----
  const float* vcol = qkv + (size_t)b * TT * QKV_N + D_MODEL + HEAD_DIM + tid;
  float a0 = 0.f, a1 = 0.f, a2 = 0.f, a3 = 0.f;
  int s = 0;
  for (; s + 3 <= t; s += 4) {
    a0 += sc[s]     * vcol[(size_t)(s)     * QKV_N];
    a1 += sc[s + 1] * vcol[(size_t)(s + 1) * QKV_N];
    a2 += sc[s + 2] * vcol[(size_t)(s + 2) * QKV_N];
    a3 += sc[s + 3] * vcol[(size_t)(s + 3) * QKV_N];
  }
  for (; s <= t; s++) a0 += sc[s] * vcol[(size_t)s * QKV_N];
  const float acc = (a0 + a1 + a2 + a3) * (1.0f / l);

  attn_out[((size_t)(b * TT + t) * NUM_HEADS + h) * HEAD_DIM + tid] = acc;
}

// ---------------------------------------------------------------------------
extern "C" void kernel_launch(void* const* d_in, const int* in_sizes, int n_in,
                              void* d_out, int out_size, void* d_ws, size_t ws_size,
                              hipStream_t stream)
{
  const float* x      = (const float*)d_in[0]; // (2,2048,2048)
  const float* sin_t  = (const float*)d_in[1]; // (2048,64)
  const float* cos_t  = (const float*)d_in[2]; // (2048,64)
  const int*   doc    = (const int*)  d_in[3]; // (2,2048)
  const float* W_qkv  = (const float*)d_in[4]; // (2048,2304)
  const float* W_out  = (const float*)d_in[5]; // (2048,2048)
  float* out = (float*)d_out;                  // (2,2048,2048)

  const int M = BB * TT;         // 4096
  // workspace layout
  float* qkv      = (float*)d_ws;                                   // 4096*2304 f32 = 37.75 MB
  float* attn_out = (float*)((char*)d_ws + (size_t)M * QKV_N * 4);  // 4096*2048 f32 = 33.55 MB

  // 1) qkv = x @ W_qkv
  {
    dim3 grid(QKV_N / 64, M / 64);
    gemm_f32_64x64<<<grid, 256, 0, stream>>>(x, W_qkv, qkv, M, QKV_N, D_MODEL);
  }
  // 2) RoPE in-place on q heads + k
  {
    const int total = BB * TT * (NUM_HEADS + 1) * 64;
    rope_kernel<<<(total + 255) / 256, 256, 0, stream>>>(qkv, sin_t, cos_t);
  }
  // 3) attention
  {
    dim3 grid(TT, NUM_HEADS, BB);
    attn_kernel<<<grid, 128, 0, stream>>>(qkv, doc, attn_out);
  }
  // 4) out = attn_out @ W_out
  {
    dim3 grid(D_MODEL / 64, M / 64);
    gemm_f32_64x64<<<grid, 256, 0, stream>>>(attn_out, W_out, out, M, D_MODEL, D_MODEL);
  }
}

// Round 2
// 1263.021 us; speedup vs baseline: 2.8883x; 2.8883x over previous
//
#include <hip/hip_runtime.h>
#include <math.h>

#define D_MODEL 2048
#define NUM_HEADS 16
#define HEAD_DIM 128
#define BB 2
#define TT 2048
#define QKV_N 2304
#define KOFF 2048
#define VOFF 2176

typedef __attribute__((ext_vector_type(8))) short short8;
typedef __attribute__((ext_vector_type(4))) float f32x4;

static __device__ __forceinline__ short f2bf(float f) {
  union { float f; unsigned u; } x; x.f = f;
  unsigned r = (x.u + 0x7FFFu + ((x.u >> 16) & 1u)) >> 16;
  return (short)r;
}
static __device__ __forceinline__ float bf2f(unsigned short u) {
  return __uint_as_float(((unsigned)u) << 16);
}

// ---------------------------------------------------------------------------
// Tiled GEMM: C[M,N] = A[M,K] @ B[K,N], row-major. A fp32 or bf16.
// 64x64 tile, BK=16, 256 threads, 4x4 micro-tile.
// ---------------------------------------------------------------------------
template <bool ABF16>
__global__ __launch_bounds__(256) void gemm64(
    const void* __restrict__ Av, const float* __restrict__ B,
    float* __restrict__ C, int M, int N, int K)
{
  __shared__ float As[16][64];
  __shared__ float Bs[16][64];
  const int tid = threadIdx.x;
  const int tx = tid & 15;
  const int ty = tid >> 4;
  const int m0 = blockIdx.y * 64;
  const int n0 = blockIdx.x * 64;

  const int a_row = tid >> 2;
  const int a_col = (tid & 3) << 2;
  const int b_row = tid >> 4;
  const int b_col = (tid & 15) << 2;

  float acc[4][4] = {{0.f}};

  for (int k0 = 0; k0 < K; k0 += 16) {
    float a0, a1, a2, a3;
    if constexpr (ABF16) {
      const short* A = (const short*)Av;
      ushort4 t = *(const ushort4*)(A + (size_t)(m0 + a_row) * K + k0 + a_col);
      a0 = bf2f(t.x); a1 = bf2f(t.y); a2 = bf2f(t.z); a3 = bf2f(t.w);
    } else {
      const float* A = (const float*)Av;
      float4 av = *(const float4*)(A + (size_t)(m0 + a_row) * K + k0 + a_col);
      a0 = av.x; a1 = av.y; a2 = av.z; a3 = av.w;
    }
    const float4 bv = *(const float4*)&B[(size_t)(k0 + b_row) * N + n0 + b_col];
    __syncthreads();
    As[a_col + 0][a_row] = a0;
    As[a_col + 1][a_row] = a1;
    As[a_col + 2][a_row] = a2;
    As[a_col + 3][a_row] = a3;
    *(float4*)&Bs[b_row][b_col] = bv;
    __syncthreads();
#pragma unroll
    for (int kk = 0; kk < 16; kk++) {
      float a[4], b[4];
#pragma unroll
      for (int i = 0; i < 4; i++) a[i] = As[kk][ty * 4 + i];
#pragma unroll
      for (int j = 0; j < 4; j++) b[j] = Bs[kk][tx * 4 + j];
#pragma unroll
      for (int i = 0; i < 4; i++)
#pragma unroll
        for (int j = 0; j < 4; j++) acc[i][j] += a[i] * b[j];
    }
  }

#pragma unroll
  for (int i = 0; i < 4; i++) {
    const int m = m0 + ty * 4 + i;
    float4 out;
    out.x = acc[i][0]; out.y = acc[i][1]; out.z = acc[i][2]; out.w = acc[i][3];
    *(float4*)&C[(size_t)m * N + n0 + tx * 4] = out;
  }
}

// ---------------------------------------------------------------------------
// RoPE in-place on qkv (q heads + k).
// ---------------------------------------------------------------------------
__global__ __launch_bounds__(256) void rope_kernel(
    float* __restrict__ qkv, const float* __restrict__ sin_t,
    const float* __restrict__ cos_t)
{
  const int idx = blockIdx.x * 256 + threadIdx.x;
  const int pairs_per_row = (NUM_HEADS + 1) * 64;
  const int total = BB * TT * pairs_per_row;
  if (idx >= total) return;
  const int p  = idx % pairs_per_row;
  const int bt = idx / pairs_per_row;
  const int t  = bt % TT;
  const int h  = p >> 6;
  const int i  = p & 63;
  const float s = sin_t[t * 64 + i];
  const float c = cos_t[t * 64 + i];
  float* base = qkv + (size_t)bt * QKV_N + h * HEAD_DIM;
  const float x1 = base[i];
  const float x2 = base[64 + i];
  base[i]      = x1 * c - x2 * s;
  base[64 + i] = x2 * c + x1 * s;
}

// ---------------------------------------------------------------------------
// Prep: K (post-rope) -> bf16 [b*T][128]; V -> bf16 transposed [b*128][T]
// ---------------------------------------------------------------------------
__global__ __launch_bounds__(256) void convert_k(
    const float* __restrict__ qkv, short* __restrict__ Kb)
{
  const int idx4 = blockIdx.x * 256 + threadIdx.x; // over B*T*32
  const int srow = idx4 >> 5;
  const int d4 = idx4 & 31;
  float4 v = *(const float4*)(qkv + (size_t)srow * QKV_N + KOFF + d4 * 4);
  short4 o;
  o.x = f2bf(v.x); o.y = f2bf(v.y); o.z = f2bf(v.z); o.w = f2bf(v.w);
  *(short4*)(Kb + ((size_t)srow << 7) + d4 * 4) = o;
}

__global__ __launch_bounds__(256) void transpose_v(
    const float* __restrict__ qkv, short* __restrict__ Vtb)
{
  const int s = blockIdx.x * 256 + threadIdx.x;
  const int n = blockIdx.y;
  const int b = blockIdx.z;
  const float v = qkv[(size_t)(b * TT + s) * QKV_N + VOFF + n];
  Vtb[((size_t)(b * 128 + n) << 11) + s] = f2bf(v);
}

// ---------------------------------------------------------------------------
// Flash MQA attention, bf16 MFMA 16x16x32.
// Block = (q-tile of 64, head, batch); 4 waves, wave owns 16 q rows.
// ---------------------------------------------------------------------------
#define KSTR 136   // Ks row stride (elems): 128 + 8 pad, keeps 16B align, no conflicts
#define VSTR 72    // Vt row stride: 64 + 8 pad
#define PSTR 72
#define MASKV -3.0e38f

__global__ __launch_bounds__(256, 3) void attn_mfma(
    const float* __restrict__ qkv, const short* __restrict__ Kb,
    const short* __restrict__ Vtb, const int* __restrict__ doc_ids,
    short* __restrict__ attn_out)
{
  __shared__ short Ks[64 * KSTR];        // 17408 B
  __shared__ short Vt[128 * VSTR];       // 18432 B
  __shared__ short Pbuf[4 * 16 * PSTR];  //  9216 B
  __shared__ int doc_s[64];

  const int qt = blockIdx.x, h = blockIdx.y, b = blockIdx.z;
  const int q0 = qt * 64;
  const int tid = threadIdx.x;
  const int w = tid >> 6;
  const int lane = tid & 63;
  const int quad = lane >> 4, l16 = lane & 15;

  // Q fragments (A-operand: A[m=l16][k=quad*8+j]), rows q0 + w*16 + l16
  const float* qp = qkv + (size_t)(b * TT + q0 + w * 16 + l16) * QKV_N
                    + h * HEAD_DIM + quad * 8;
  short8 Qf[4];
#pragma unroll
  for (int kc = 0; kc < 4; kc++) {
    float4 x0 = *(const float4*)(qp + kc * 32);
    float4 x1 = *(const float4*)(qp + kc * 32 + 4);
    short8 q;
    q[0] = f2bf(x0.x); q[1] = f2bf(x0.y); q[2] = f2bf(x0.z); q[3] = f2bf(x0.w);
    q[4] = f2bf(x1.x); q[5] = f2bf(x1.y); q[6] = f2bf(x1.z); q[7] = f2bf(x1.w);
    Qf[kc] = q;
  }

  // per-lane row state: C-layout rows quad*4+r (replicated over 16 lanes/quad)
  int qg[4], mydoc[4];
  float m_i[4], l_i[4];
#pragma unroll
  for (int r = 0; r < 4; r++) {
    qg[r] = q0 + w * 16 + quad * 4 + r;
    mydoc[r] = doc_ids[b * TT + qg[r]];
    m_i[r] = MASKV;
    l_i[r] = 0.f;
  }
  f32x4 O[8];
#pragma unroll
  for (int v8 = 0; v8 < 8; v8++) O[v8] = (f32x4){0.f, 0.f, 0.f, 0.f};

  short* Pw = Pbuf + w * 16 * PSTR;
  const float scale = 0.08838834764831844f;

  for (int st = 0; st <= qt; st++) {
    const int s0 = st * 64;
    __syncthreads();  // previous iteration's LDS reads done
    // stage K tile: 64 rows x 128 bf16
#pragma unroll
    for (int i = 0; i < 4; i++) {
      int f = i * 256 + tid;
      int row = f >> 4, seg = f & 15;
      int4 v = *(const int4*)(Kb + ((size_t)(b * TT + s0 + row) << 7) + seg * 8);
      *(int4*)(Ks + row * KSTR + seg * 8) = v;
    }
    // stage V tile (already transposed): 128 n-rows x 64 bf16
#pragma unroll
    for (int i = 0; i < 4; i++) {
      int f = i * 256 + tid;
      int n = f >> 3, seg = f & 7;
      int4 v = *(const int4*)(Vtb + ((size_t)(b * 128 + n) << 11) + s0 + seg * 8);
      *(int4*)(Vt + n * VSTR + seg * 8) = v;
    }
    if (tid < 64) doc_s[tid] = doc_ids[b * TT + s0 + tid];
    __syncthreads();

    // ---- S = Q K^T  (B-frag: B[k=d][n=s] from row-major K tile) ----
    f32x4 S[4];
#pragma unroll
    for (int ns = 0; ns < 4; ns++) {
      f32x4 acc = (f32x4){0.f, 0.f, 0.f, 0.f};
      const short* kr = Ks + (ns * 16 + l16) * KSTR + quad * 8;
#pragma unroll
      for (int kc = 0; kc < 4; kc++) {
        short8 kf = *(const short8*)(kr + kc * 32);
        acc = __builtin_amdgcn_mfma_f32_16x16x32_bf16(Qf[kc], kf, acc, 0, 0, 0);
      }
      S[ns] = acc;
    }

    // ---- mask + scale; tile row max ----
    float mt[4] = {MASKV, MASKV, MASKV, MASKV};
#pragma unroll
    for (int ns = 0; ns < 4; ns++) {
      const int s_loc = ns * 16 + l16;
      const int sg = s0 + s_loc;
      const int sdoc = doc_s[s_loc];
#pragma unroll
      for (int r = 0; r < 4; r++) {
        const bool ok = (sg <= qg[r]) && (sdoc == mydoc[r]);
        const float v = ok ? S[ns][r] * scale : MASKV;
        S[ns][r] = v;
        mt[r] = fmaxf(mt[r], v);
      }
    }
#pragma unroll
    for (int off = 8; off >= 1; off >>= 1)
#pragma unroll
      for (int r = 0; r < 4; r++) mt[r] = fmaxf(mt[r], __shfl_xor(mt[r], off));

    // ---- online softmax update ----
    float alpha[4], rs[4];
#pragma unroll
    for (int r = 0; r < 4; r++) {
      const float mn = fmaxf(m_i[r], mt[r]);
      alpha[r] = (mn < -1e37f) ? 1.f : __expf(m_i[r] - mn);
      m_i[r] = mn;
      rs[r] = 0.f;
    }
#pragma unroll
    for (int ns = 0; ns < 4; ns++) {
#pragma unroll
      for (int r = 0; r < 4; r++) {
        const float p = (S[ns][r] < -1e37f) ? 0.f : __expf(S[ns][r] - m_i[r]);
        rs[r] += p;
        Pw[(quad * 4 + r) * PSTR + ns * 16 + l16] = f2bf(p);  // C-layout -> LDS
      }
    }
#pragma unroll
    for (int off = 8; off >= 1; off >>= 1)
#pragma unroll
      for (int r = 0; r < 4; r++) rs[r] += __shfl_xor(rs[r], off);
#pragma unroll
    for (int r = 0; r < 4; r++) l_i[r] = l_i[r] * alpha[r] + rs[r];
#pragma unroll
    for (int v8 = 0; v8 < 8; v8++)
#pragma unroll
      for (int r = 0; r < 4; r++) O[v8][r] *= alpha[r];

    // ---- O += P V  (A-frag of P from LDS; B-frag of V^T from LDS) ----
#pragma unroll
    for (int ks = 0; ks < 2; ks++) {
      short8 pf = *(const short8*)(Pw + l16 * PSTR + ks * 32 + quad * 8);
#pragma unroll
      for (int v8 = 0; v8 < 8; v8++) {
        short8 vf = *(const short8*)(Vt + (v8 * 16 + l16) * VSTR + ks * 32 + quad * 8);
        O[v8] = __builtin_amdgcn_mfma_f32_16x16x32_bf16(pf, vf, O[v8], 0, 0, 0);
      }
    }
  }

  // ---- epilogue: O / l, bf16 store ----
#pragma unroll
  for (int r = 0; r < 4; r++) {
    const float inv = 1.f / l_i[r];
    short* op = attn_out + (size_t)(b * TT + qg[r]) * D_MODEL + h * HEAD_DIM + l16;
#pragma unroll
    for (int v8 = 0; v8 < 8; v8++)
      op[v8 * 16] = f2bf(O[v8][r] * inv);
  }
}

// ---------------------------------------------------------------------------
extern "C" void kernel_launch(void* const* d_in, const int* in_sizes, int n_in,
                              void* d_out, int out_size, void* d_ws, size_t ws_size,
                              hipStream_t stream)
{
  const float* x     = (const float*)d_in[0];
  const float* sin_t = (const float*)d_in[1];
  const float* cos_t = (const float*)d_in[2];
  const int*   doc   = (const int*)  d_in[3];
  const float* W_qkv = (const float*)d_in[4];
  const float* W_out = (const float*)d_in[5];
  float* out = (float*)d_out;

  const int M = BB * TT;  // 4096

  // workspace: qkv f32 (37.75MB) | attn bf16 (16.78MB) | Kb bf16 (1MB) | Vt bf16 (1MB)
  float* qkv = (float*)d_ws;
  char* p = (char*)d_ws + (size_t)M * QKV_N * 4;
  short* attn_bf = (short*)p; p += (size_t)M * D_MODEL * 2;
  short* Kb      = (short*)p; p += (size_t)M * HEAD_DIM * 2;
  short* Vtb     = (short*)p;

  // 1) qkv = x @ W_qkv  (fp32)
  {
    dim3 grid(QKV_N / 64, M / 64);
    gemm64<false><<<grid, 256, 0, stream>>>(x, W_qkv, qkv, M, QKV_N, D_MODEL);
  }
  // 2) RoPE in-place
  {
    const int total = BB * TT * (NUM_HEADS + 1) * 64;
    rope_kernel<<<(total + 255) / 256, 256, 0, stream>>>(qkv, sin_t, cos_t);
  }
  // 3) prep bf16 K and transposed V
  convert_k<<<(M * 32) / 256, 256, 0, stream>>>(qkv, Kb);
  {
    dim3 grid(TT / 256, HEAD_DIM, BB);
    transpose_v<<<grid, 256, 0, stream>>>(qkv, Vtb);
  }
  // 4) flash attention (bf16 MFMA)
  {
    dim3 grid(TT / 64, NUM_HEADS, BB);
    attn_mfma<<<grid, 256, 0, stream>>>(qkv, Kb, Vtb, doc, attn_bf);
  }
  // 5) out = attn @ W_out  (bf16 A, fp32 B/C)
  {
    dim3 grid(D_MODEL / 64, M / 64);
    gemm64<true><<<grid, 256, 0, stream>>>(attn_bf, W_out, out, M, D_MODEL, D_MODEL);
  }
}

// Round 3
// 432.310 us; speedup vs baseline: 8.4385x; 2.9216x over previous
//
#include <hip/hip_runtime.h>
#include <math.h>

#define D_MODEL 2048
#define NUM_HEADS 16
#define HEAD_DIM 128
#define BB 2
#define TT 2048
#define QKV_N 2304
#define KOFF 2048
#define VOFF 2176

typedef __attribute__((ext_vector_type(8))) short short8;
typedef __attribute__((ext_vector_type(4))) float f32x4;

static __device__ __forceinline__ short f2bf(float f) {
  union { float f; unsigned u; } x; x.f = f;
  unsigned r = (x.u + 0x7FFFu + ((x.u >> 16) & 1u)) >> 16;
  return (short)r;
}
static __device__ __forceinline__ float bf2f(unsigned short u) {
  return __uint_as_float(((unsigned)u) << 16);
}

#define GLD16(gp, lp)                                              \
  __builtin_amdgcn_global_load_lds(                                \
      (const __attribute__((address_space(1))) void*)(gp),         \
      (__attribute__((address_space(3))) void*)(lp), 16, 0, 0)

// ---------------------------------------------------------------------------
// bf16 MFMA GEMM (m97 structure): C[M,N] = A[M,K] @ Bt[N,K]^T.
// 128x128 tile, BK=32, 256 threads (4 waves, 2x2), 4x4 MFMAs of 16x16x32/wave.
// global->LDS via global_load_lds width=16 (LDS dest = wave base + lane*16).
// M,N % 128 == 0, K % 32 == 0.
// ---------------------------------------------------------------------------
template <bool OUT_BF16>
__global__ __launch_bounds__(256) void gemm_mfma_bt(
    const short* __restrict__ A, const short* __restrict__ Bt,
    void* __restrict__ Cv, int M, int N, int K)
{
  __shared__ short As[128 * 32];  // [m][k] row-major, 8 KB
  __shared__ short Bs[128 * 32];  // [n][k] row-major, 8 KB

  const int tid = threadIdx.x;
  const int w = tid >> 6, l = tid & 63;
  const int quad = l >> 4, l16 = l & 15;
  const int wm = w >> 1, wn = w & 1;
  const int m0 = blockIdx.y * 128, n0 = blockIdx.x * 128;

  f32x4 acc[4][4];
#pragma unroll
  for (int i = 0; i < 4; i++)
#pragma unroll
    for (int j = 0; j < 4; j++) acc[i][j] = (f32x4){0.f, 0.f, 0.f, 0.f};

  // staging: wave w owns row segments {2w, 2w+1} (16 rows each);
  // lane l covers row seg*16 + l/4, k-cols (l%4)*8 .. +7  (16 B)
  const short* aA = A + (size_t)(m0 + w * 32 + (l >> 2)) * K + (l & 3) * 8;
  const short* aB = Bt + (size_t)(n0 + w * 32 + (l >> 2)) * K + (l & 3) * 8;
  short* lA0 = As + (w * 2) * 512;      // wave-uniform LDS bases
  short* lA1 = As + (w * 2 + 1) * 512;
  short* lB0 = Bs + (w * 2) * 512;
  short* lB1 = Bs + (w * 2 + 1) * 512;

  const short* Ard = As + (size_t)(wm * 64 + l16) * 32 + quad * 8;
  const short* Brd = Bs + (size_t)(wn * 64 + l16) * 32 + quad * 8;

  for (int k0 = 0; k0 < K; k0 += 32) {
    __syncthreads();  // previous iteration's LDS reads done
    GLD16(aA + k0, lA0);
    GLD16(aA + k0 + (size_t)16 * K, lA1);
    GLD16(aB + k0, lB0);
    GLD16(aB + k0 + (size_t)16 * K, lB1);
    __syncthreads();

    short8 af[4], bf[4];
#pragma unroll
    for (int mi = 0; mi < 4; mi++) af[mi] = *(const short8*)(Ard + mi * 16 * 32);
#pragma unroll
    for (int ni = 0; ni < 4; ni++) bf[ni] = *(const short8*)(Brd + ni * 16 * 32);
#pragma unroll
    for (int mi = 0; mi < 4; mi++)
#pragma unroll
      for (int ni = 0; ni < 4; ni++)
        acc[mi][ni] =
            __builtin_amdgcn_mfma_f32_16x16x32_bf16(af[mi], bf[ni], acc[mi][ni], 0, 0, 0);
  }

  // epilogue: C row = quad*4 + r, col = l16
#pragma unroll
  for (int mi = 0; mi < 4; mi++) {
#pragma unroll
    for (int ni = 0; ni < 4; ni++) {
#pragma unroll
      for (int r = 0; r < 4; r++) {
        const int row = m0 + wm * 64 + mi * 16 + quad * 4 + r;
        const int col = n0 + wn * 64 + ni * 16 + l16;
        if constexpr (OUT_BF16)
          ((short*)Cv)[(size_t)row * N + col] = f2bf(acc[mi][ni][r]);
        else
          ((float*)Cv)[(size_t)row * N + col] = acc[mi][ni][r];
      }
    }
  }
}

// ---------------------------------------------------------------------------
// x (fp32) -> bf16, elementwise
// ---------------------------------------------------------------------------
__global__ __launch_bounds__(256) void convert_x(
    const float* __restrict__ x, short* __restrict__ xb)
{
  const size_t i4 = (size_t)blockIdx.x * 256 + threadIdx.x;
  float4 v = *(const float4*)(x + i4 * 4);
  short4 o;
  o.x = f2bf(v.x); o.y = f2bf(v.y); o.z = f2bf(v.z); o.w = f2bf(v.w);
  *(short4*)(xb + i4 * 4) = o;
}

// ---------------------------------------------------------------------------
// W [K][N] fp32 -> Wt [N][K] bf16, LDS-tiled 32x32
// ---------------------------------------------------------------------------
__global__ __launch_bounds__(256) void transpose_w_bf(
    const float* __restrict__ W, short* __restrict__ Wt, int K, int N)
{
  __shared__ float t[32][33];
  const int tx = threadIdx.x, ty = threadIdx.y;
  const int n0 = blockIdx.x * 32, k0 = blockIdx.y * 32;
#pragma unroll
  for (int j = 0; j < 4; j++)
    t[ty + j * 8][tx] = W[(size_t)(k0 + ty + j * 8) * N + n0 + tx];
  __syncthreads();
#pragma unroll
  for (int j = 0; j < 4; j++)
    Wt[(size_t)(n0 + ty + j * 8) * K + k0 + tx] = f2bf(t[tx][ty + j * 8]);
}

// ---------------------------------------------------------------------------
// RoPE in-place on bf16 qkv (q heads + k head)
// ---------------------------------------------------------------------------
__global__ __launch_bounds__(256) void rope_bf(
    short* __restrict__ qkv, const float* __restrict__ sin_t,
    const float* __restrict__ cos_t)
{
  const int idx = blockIdx.x * 256 + threadIdx.x;
  const int pairs_per_row = (NUM_HEADS + 1) * 64;
  const int total = BB * TT * pairs_per_row;
  if (idx >= total) return;
  const int p  = idx % pairs_per_row;
  const int bt = idx / pairs_per_row;
  const int t  = bt % TT;
  const int h  = p >> 6;
  const int i  = p & 63;
  const float s = sin_t[t * 64 + i];
  const float c = cos_t[t * 64 + i];
  short* base = qkv + (size_t)bt * QKV_N + h * HEAD_DIM;
  const float x1 = bf2f((unsigned short)base[i]);
  const float x2 = bf2f((unsigned short)base[64 + i]);
  base[i]      = f2bf(x1 * c - x2 * s);
  base[64 + i] = f2bf(x2 * c + x1 * s);
}

// ---------------------------------------------------------------------------
// V slice of bf16 qkv -> Vt [b*128][T] bf16
// ---------------------------------------------------------------------------
__global__ __launch_bounds__(256) void transpose_v(
    const short* __restrict__ qkv, short* __restrict__ Vtb)
{
  const int s = blockIdx.x * 256 + threadIdx.x;
  const int n = blockIdx.y;
  const int b = blockIdx.z;
  Vtb[((size_t)(b * 128 + n) << 11) + s] =
      qkv[(size_t)(b * TT + s) * QKV_N + VOFF + n];
}

// ---------------------------------------------------------------------------
// Flash MQA attention, bf16 MFMA 16x16x32 (verified round 2).
// Q/K read straight from bf16 qkv; V from pre-transposed Vtb.
// ---------------------------------------------------------------------------
#define KSTR 136
#define VSTR 72
#define PSTR 72
#define MASKV -3.0e38f

__global__ __launch_bounds__(256, 3) void attn_mfma(
    const short* __restrict__ qkv, const short* __restrict__ Vtb,
    const int* __restrict__ doc_ids, short* __restrict__ attn_out)
{
  __shared__ short Ks[64 * KSTR];
  __shared__ short Vt[128 * VSTR];
  __shared__ short Pbuf[4 * 16 * PSTR];
  __shared__ int doc_s[64];

  const int qt = blockIdx.x, h = blockIdx.y, b = blockIdx.z;
  const int q0 = qt * 64;
  const int tid = threadIdx.x;
  const int w = tid >> 6;
  const int lane = tid & 63;
  const int quad = lane >> 4, l16 = lane & 15;

  // Q fragments straight from bf16 qkv
  const short* qp = qkv + (size_t)(b * TT + q0 + w * 16 + l16) * QKV_N
                    + h * HEAD_DIM + quad * 8;
  short8 Qf[4];
#pragma unroll
  for (int kc = 0; kc < 4; kc++) Qf[kc] = *(const short8*)(qp + kc * 32);

  int qg[4], mydoc[4];
  float m_i[4], l_i[4];
#pragma unroll
  for (int r = 0; r < 4; r++) {
    qg[r] = q0 + w * 16 + quad * 4 + r;
    mydoc[r] = doc_ids[b * TT + qg[r]];
    m_i[r] = MASKV;
    l_i[r] = 0.f;
  }
  f32x4 O[8];
#pragma unroll
  for (int v8 = 0; v8 < 8; v8++) O[v8] = (f32x4){0.f, 0.f, 0.f, 0.f};

  short* Pw = Pbuf + w * 16 * PSTR;
  const float scale = 0.08838834764831844f;

  for (int st = 0; st <= qt; st++) {
    const int s0 = st * 64;
    __syncthreads();
#pragma unroll
    for (int i = 0; i < 4; i++) {
      int f = i * 256 + tid;
      int row = f >> 4, seg = f & 15;
      int4 v = *(const int4*)(qkv + (size_t)(b * TT + s0 + row) * QKV_N + KOFF + seg * 8);
      *(int4*)(Ks + row * KSTR + seg * 8) = v;
    }
#pragma unroll
    for (int i = 0; i < 4; i++) {
      int f = i * 256 + tid;
      int n = f >> 3, seg = f & 7;
      int4 v = *(const int4*)(Vtb + ((size_t)(b * 128 + n) << 11) + s0 + seg * 8);
      *(int4*)(Vt + n * VSTR + seg * 8) = v;
    }
    if (tid < 64) doc_s[tid] = doc_ids[b * TT + s0 + tid];
    __syncthreads();

    f32x4 S[4];
#pragma unroll
    for (int ns = 0; ns < 4; ns++) {
      f32x4 acc = (f32x4){0.f, 0.f, 0.f, 0.f};
      const short* kr = Ks + (ns * 16 + l16) * KSTR + quad * 8;
#pragma unroll
      for (int kc = 0; kc < 4; kc++) {
        short8 kf = *(const short8*)(kr + kc * 32);
        acc = __builtin_amdgcn_mfma_f32_16x16x32_bf16(Qf[kc], kf, acc, 0, 0, 0);
      }
      S[ns] = acc;
    }

    float mt[4] = {MASKV, MASKV, MASKV, MASKV};
#pragma unroll
    for (int ns = 0; ns < 4; ns++) {
      const int s_loc = ns * 16 + l16;
      const int sg = s0 + s_loc;
      const int sdoc = doc_s[s_loc];
#pragma unroll
      for (int r = 0; r < 4; r++) {
        const bool ok = (sg <= qg[r]) && (sdoc == mydoc[r]);
        const float v = ok ? S[ns][r] * scale : MASKV;
        S[ns][r] = v;
        mt[r] = fmaxf(mt[r], v);
      }
    }
#pragma unroll
    for (int off = 8; off >= 1; off >>= 1)
#pragma unroll
      for (int r = 0; r < 4; r++) mt[r] = fmaxf(mt[r], __shfl_xor(mt[r], off));

    float alpha[4], rs[4];
#pragma unroll
    for (int r = 0; r < 4; r++) {
      const float mn = fmaxf(m_i[r], mt[r]);
      alpha[r] = (mn < -1e37f) ? 1.f : __expf(m_i[r] - mn);
      m_i[r] = mn;
      rs[r] = 0.f;
    }
#pragma unroll
    for (int ns = 0; ns < 4; ns++) {
#pragma unroll
      for (int r = 0; r < 4; r++) {
        const float p = (S[ns][r] < -1e37f) ? 0.f : __expf(S[ns][r] - m_i[r]);
        rs[r] += p;
        Pw[(quad * 4 + r) * PSTR + ns * 16 + l16] = f2bf(p);
      }
    }
#pragma unroll
    for (int off = 8; off >= 1; off >>= 1)
#pragma unroll
      for (int r = 0; r < 4; r++) rs[r] += __shfl_xor(rs[r], off);
#pragma unroll
    for (int r = 0; r < 4; r++) l_i[r] = l_i[r] * alpha[r] + rs[r];
#pragma unroll
    for (int v8 = 0; v8 < 8; v8++)
#pragma unroll
      for (int r = 0; r < 4; r++) O[v8][r] *= alpha[r];

#pragma unroll
    for (int ks = 0; ks < 2; ks++) {
      short8 pf = *(const short8*)(Pw + l16 * PSTR + ks * 32 + quad * 8);
#pragma unroll
      for (int v8 = 0; v8 < 8; v8++) {
        short8 vf = *(const short8*)(Vt + (v8 * 16 + l16) * VSTR + ks * 32 + quad * 8);
        O[v8] = __builtin_amdgcn_mfma_f32_16x16x32_bf16(pf, vf, O[v8], 0, 0, 0);
      }
    }
  }

#pragma unroll
  for (int r = 0; r < 4; r++) {
    const float inv = 1.f / l_i[r];
    short* op = attn_out + (size_t)(b * TT + qg[r]) * D_MODEL + h * HEAD_DIM + l16;
#pragma unroll
    for (int v8 = 0; v8 < 8; v8++)
      op[v8 * 16] = f2bf(O[v8][r] * inv);
  }
}

// ---------------------------------------------------------------------------
extern "C" void kernel_launch(void* const* d_in, const int* in_sizes, int n_in,
                              void* d_out, int out_size, void* d_ws, size_t ws_size,
                              hipStream_t stream)
{
  const float* x     = (const float*)d_in[0];
  const float* sin_t = (const float*)d_in[1];
  const float* cos_t = (const float*)d_in[2];
  const int*   doc   = (const int*)  d_in[3];
  const float* W_qkv = (const float*)d_in[4];
  const float* W_out = (const float*)d_in[5];
  float* out = (float*)d_out;

  const int M = BB * TT;  // 4096

  // workspace: qkv_bf (18.87MB) | xb/attn_bf alias (16.78MB) | Vtb (1.05MB)
  //          | Wqkv_t (9.44MB)  | Wout_t (8.39MB)   -> total ~54.5 MB
  char* p = (char*)d_ws;
  short* qkv_bf = (short*)p; p += (size_t)M * QKV_N * 2;
  short* xb     = (short*)p; p += (size_t)M * D_MODEL * 2;
  short* attn_bf = xb;  // alias: xb dead after GEMM1
  short* Vtb    = (short*)p; p += (size_t)BB * 128 * TT * 2;
  short* Wqkv_t = (short*)p; p += (size_t)QKV_N * D_MODEL * 2;
  short* Wout_t = (short*)p;

  // 0) preps: x->bf16; W->bf16 transposed
  convert_x<<<(M * D_MODEL / 4) / 256, 256, 0, stream>>>(x, xb);
  {
    dim3 grid(QKV_N / 32, D_MODEL / 32), blk(32, 8);
    transpose_w_bf<<<grid, blk, 0, stream>>>(W_qkv, Wqkv_t, D_MODEL, QKV_N);
  }
  {
    dim3 grid(D_MODEL / 32, D_MODEL / 32), blk(32, 8);
    transpose_w_bf<<<grid, blk, 0, stream>>>(W_out, Wout_t, D_MODEL, D_MODEL);
  }
  // 1) qkv = x @ W_qkv  (bf16 MFMA, bf16 out)
  {
    dim3 grid(QKV_N / 128, M / 128);
    gemm_mfma_bt<true><<<grid, 256, 0, stream>>>(xb, Wqkv_t, qkv_bf, M, QKV_N, D_MODEL);
  }
  // 2) RoPE in-place (bf16)
  {
    const int total = BB * TT * (NUM_HEADS + 1) * 64;
    rope_bf<<<(total + 255) / 256, 256, 0, stream>>>(qkv_bf, sin_t, cos_t);
  }
  // 3) V transpose
  {
    dim3 grid(TT / 256, HEAD_DIM, BB);
    transpose_v<<<grid, 256, 0, stream>>>(qkv_bf, Vtb);
  }
  // 4) flash attention
  {
    dim3 grid(TT / 64, NUM_HEADS, BB);
    attn_mfma<<<grid, 256, 0, stream>>>(qkv_bf, Vtb, doc, attn_bf);
  }
  // 5) out = attn @ W_out  (bf16 MFMA, fp32 out)
  {
    dim3 grid(D_MODEL / 128, M / 128);
    gemm_mfma_bt<false><<<grid, 256, 0, stream>>>(attn_bf, Wout_t, out, M, D_MODEL, D_MODEL);
  }
}

// Round 4
// 314.056 us; speedup vs baseline: 11.6158x; 1.3765x over previous
//
#include <hip/hip_runtime.h>
#include <math.h>

#define D_MODEL 2048
#define NUM_HEADS 16
#define HEAD_DIM 128
#define BB 2
#define TT 2048
#define QKV_N 2304
#define KOFF 2048
#define VOFF 2176

typedef __attribute__((ext_vector_type(8))) short short8;
typedef __attribute__((ext_vector_type(4))) float f32x4;

static __device__ __forceinline__ short f2bf(float f) {
  union { float f; unsigned u; } x; x.f = f;
  unsigned r = (x.u + 0x7FFFu + ((x.u >> 16) & 1u)) >> 16;
  return (short)r;
}
static __device__ __forceinline__ float bf2f(unsigned short u) {
  return __uint_as_float(((unsigned)u) << 16);
}

#define GLD16(gp, lp)                                              \
  __builtin_amdgcn_global_load_lds(                                \
      (const __attribute__((address_space(1))) void*)(gp),         \
      (__attribute__((address_space(3))) void*)(lp), 16, 0, 0)

// ---------------------------------------------------------------------------
// bf16 MFMA GEMM (m97 structure): C[M,N] = A[M,K] @ Bt[N,K]^T.
// 128x128 tile, BK=32, 256 threads (4 waves, 2x2), 4x4 MFMAs of 16x16x32/wave.
// ---------------------------------------------------------------------------
template <bool OUT_BF16>
__global__ __launch_bounds__(256) void gemm_mfma_bt(
    const short* __restrict__ A, const short* __restrict__ Bt,
    void* __restrict__ Cv, int M, int N, int K)
{
  __shared__ short As[128 * 32];
  __shared__ short Bs[128 * 32];

  const int tid = threadIdx.x;
  const int w = tid >> 6, l = tid & 63;
  const int quad = l >> 4, l16 = l & 15;
  const int wm = w >> 1, wn = w & 1;
  const int m0 = blockIdx.y * 128, n0 = blockIdx.x * 128;

  f32x4 acc[4][4];
#pragma unroll
  for (int i = 0; i < 4; i++)
#pragma unroll
    for (int j = 0; j < 4; j++) acc[i][j] = (f32x4){0.f, 0.f, 0.f, 0.f};

  const short* aA = A + (size_t)(m0 + w * 32 + (l >> 2)) * K + (l & 3) * 8;
  const short* aB = Bt + (size_t)(n0 + w * 32 + (l >> 2)) * K + (l & 3) * 8;
  short* lA0 = As + (w * 2) * 512;
  short* lA1 = As + (w * 2 + 1) * 512;
  short* lB0 = Bs + (w * 2) * 512;
  short* lB1 = Bs + (w * 2 + 1) * 512;

  const short* Ard = As + (size_t)(wm * 64 + l16) * 32 + quad * 8;
  const short* Brd = Bs + (size_t)(wn * 64 + l16) * 32 + quad * 8;

  for (int k0 = 0; k0 < K; k0 += 32) {
    __syncthreads();
    GLD16(aA + k0, lA0);
    GLD16(aA + k0 + (size_t)16 * K, lA1);
    GLD16(aB + k0, lB0);
    GLD16(aB + k0 + (size_t)16 * K, lB1);
    __syncthreads();

    short8 af[4], bf[4];
#pragma unroll
    for (int mi = 0; mi < 4; mi++) af[mi] = *(const short8*)(Ard + mi * 16 * 32);
#pragma unroll
    for (int ni = 0; ni < 4; ni++) bf[ni] = *(const short8*)(Brd + ni * 16 * 32);
#pragma unroll
    for (int mi = 0; mi < 4; mi++)
#pragma unroll
      for (int ni = 0; ni < 4; ni++)
        acc[mi][ni] =
            __builtin_amdgcn_mfma_f32_16x16x32_bf16(af[mi], bf[ni], acc[mi][ni], 0, 0, 0);
  }

#pragma unroll
  for (int mi = 0; mi < 4; mi++) {
#pragma unroll
    for (int ni = 0; ni < 4; ni++) {
#pragma unroll
      for (int r = 0; r < 4; r++) {
        const int row = m0 + wm * 64 + mi * 16 + quad * 4 + r;
        const int col = n0 + wn * 64 + ni * 16 + l16;
        if constexpr (OUT_BF16)
          ((short*)Cv)[(size_t)row * N + col] = f2bf(acc[mi][ni][r]);
        else
          ((float*)Cv)[(size_t)row * N + col] = acc[mi][ni][r];
      }
    }
  }
}

// ---------------------------------------------------------------------------
__global__ __launch_bounds__(256) void convert_x(
    const float* __restrict__ x, short* __restrict__ xb)
{
  const size_t i4 = (size_t)blockIdx.x * 256 + threadIdx.x;
  float4 v = *(const float4*)(x + i4 * 4);
  short4 o;
  o.x = f2bf(v.x); o.y = f2bf(v.y); o.z = f2bf(v.z); o.w = f2bf(v.w);
  *(short4*)(xb + i4 * 4) = o;
}

__global__ __launch_bounds__(256) void transpose_w_bf(
    const float* __restrict__ W, short* __restrict__ Wt, int K, int N)
{
  __shared__ float t[32][33];
  const int tx = threadIdx.x, ty = threadIdx.y;
  const int n0 = blockIdx.x * 32, k0 = blockIdx.y * 32;
#pragma unroll
  for (int j = 0; j < 4; j++)
    t[ty + j * 8][tx] = W[(size_t)(k0 + ty + j * 8) * N + n0 + tx];
  __syncthreads();
#pragma unroll
  for (int j = 0; j < 4; j++)
    Wt[(size_t)(n0 + ty + j * 8) * K + k0 + tx] = f2bf(t[tx][ty + j * 8]);
}

__global__ __launch_bounds__(256) void rope_bf(
    short* __restrict__ qkv, const float* __restrict__ sin_t,
    const float* __restrict__ cos_t)
{
  const int idx = blockIdx.x * 256 + threadIdx.x;
  const int pairs_per_row = (NUM_HEADS + 1) * 64;
  const int total = BB * TT * pairs_per_row;
  if (idx >= total) return;
  const int p  = idx % pairs_per_row;
  const int bt = idx / pairs_per_row;
  const int t  = bt % TT;
  const int h  = p >> 6;
  const int i  = p & 63;
  const float s = sin_t[t * 64 + i];
  const float c = cos_t[t * 64 + i];
  short* base = qkv + (size_t)bt * QKV_N + h * HEAD_DIM;
  const float x1 = bf2f((unsigned short)base[i]);
  const float x2 = bf2f((unsigned short)base[64 + i]);
  base[i]      = f2bf(x1 * c - x2 * s);
  base[64 + i] = f2bf(x2 * c + x1 * s);
}

__global__ __launch_bounds__(256) void transpose_v(
    const short* __restrict__ qkv, short* __restrict__ Vtb)
{
  const int s = blockIdx.x * 256 + threadIdx.x;
  const int n = blockIdx.y;
  const int b = blockIdx.z;
  Vtb[((size_t)(b * 128 + n) << 11) + s] =
      qkv[(size_t)(b * TT + s) * QKV_N + VOFF + n];
}

// ---------------------------------------------------------------------------
// Flash MQA attention, bf16 MFMA 16x16x32, doc-block-sparse.
// doc_ids sorted along t => skip s-tile iff doc[s0+63] < doc[q0] (exact);
// fully-unmasked fast path iff st<qt && doc[s0]==doc[q0+63].
// ---------------------------------------------------------------------------
#define KSTR 136
#define VSTR 72
#define PSTR 72
#define MASKV -3.0e38f

__global__ __launch_bounds__(256) void attn_mfma(
    const short* __restrict__ qkv, const short* __restrict__ Vtb,
    const int* __restrict__ doc_ids, short* __restrict__ attn_out)
{
  __shared__ short Ks[64 * KSTR];
  __shared__ short Vt[128 * VSTR];
  __shared__ short Pbuf[4 * 16 * PSTR];
  __shared__ int doc_s[64];

  const int qt = blockIdx.x, h = blockIdx.y, b = blockIdx.z;
  const int q0 = qt * 64;
  const int tid = threadIdx.x;
  const int w = tid >> 6;
  const int lane = tid & 63;
  const int quad = lane >> 4, l16 = lane & 15;

  const short* qp = qkv + (size_t)(b * TT + q0 + w * 16 + l16) * QKV_N
                    + h * HEAD_DIM + quad * 8;
  short8 Qf[4];
#pragma unroll
  for (int kc = 0; kc < 4; kc++) Qf[kc] = *(const short8*)(qp + kc * 32);

  const int docmin_q = doc_ids[b * TT + q0];
  const int docmax_q = doc_ids[b * TT + q0 + 63];

  int qg[4], mydoc[4];
  float m_i[4], l_i[4];
#pragma unroll
  for (int r = 0; r < 4; r++) {
    qg[r] = q0 + w * 16 + quad * 4 + r;
    mydoc[r] = doc_ids[b * TT + qg[r]];
    m_i[r] = MASKV;
    l_i[r] = 0.f;
  }
  f32x4 O[8];
#pragma unroll
  for (int v8 = 0; v8 < 8; v8++) O[v8] = (f32x4){0.f, 0.f, 0.f, 0.f};

  short* Pw = Pbuf + w * 16 * PSTR;
  const float scale = 0.08838834764831844f;

  for (int st = 0; st <= qt; st++) {
    const int s0 = st * 64;
    // exact tile-level doc skip (block-uniform): all s docs < all q docs
    const int dmin_s = doc_ids[b * TT + s0];
    const int dmax_s = doc_ids[b * TT + s0 + 63];
    if (dmax_s < docmin_q) continue;
    const bool full = (st < qt) && (dmin_s == docmax_q);  // all docs equal, causal auto

    __syncthreads();
#pragma unroll
    for (int i = 0; i < 4; i++) {
      int f = i * 256 + tid;
      int row = f >> 4, seg = f & 15;
      int4 v = *(const int4*)(qkv + (size_t)(b * TT + s0 + row) * QKV_N + KOFF + seg * 8);
      *(int4*)(Ks + row * KSTR + seg * 8) = v;
    }
#pragma unroll
    for (int i = 0; i < 4; i++) {
      int f = i * 256 + tid;
      int n = f >> 3, seg = f & 7;
      int4 v = *(const int4*)(Vtb + ((size_t)(b * 128 + n) << 11) + s0 + seg * 8);
      *(int4*)(Vt + n * VSTR + seg * 8) = v;
    }
    if (!full && tid < 64) doc_s[tid] = doc_ids[b * TT + s0 + tid];
    __syncthreads();

    f32x4 S[4];
#pragma unroll
    for (int ns = 0; ns < 4; ns++) {
      f32x4 acc = (f32x4){0.f, 0.f, 0.f, 0.f};
      const short* kr = Ks + (ns * 16 + l16) * KSTR + quad * 8;
#pragma unroll
      for (int kc = 0; kc < 4; kc++) {
        short8 kf = *(const short8*)(kr + kc * 32);
        acc = __builtin_amdgcn_mfma_f32_16x16x32_bf16(Qf[kc], kf, acc, 0, 0, 0);
      }
      S[ns] = acc;
    }

    float mt[4] = {MASKV, MASKV, MASKV, MASKV};
    if (full) {
#pragma unroll
      for (int ns = 0; ns < 4; ns++)
#pragma unroll
        for (int r = 0; r < 4; r++) {
          const float v = S[ns][r] * scale;
          S[ns][r] = v;
          mt[r] = fmaxf(mt[r], v);
        }
    } else {
#pragma unroll
      for (int ns = 0; ns < 4; ns++) {
        const int s_loc = ns * 16 + l16;
        const int sg = s0 + s_loc;
        const int sdoc = doc_s[s_loc];
#pragma unroll
        for (int r = 0; r < 4; r++) {
          const bool ok = (sg <= qg[r]) && (sdoc == mydoc[r]);
          const float v = ok ? S[ns][r] * scale : MASKV;
          S[ns][r] = v;
          mt[r] = fmaxf(mt[r], v);
        }
      }
    }
#pragma unroll
    for (int off = 8; off >= 1; off >>= 1)
#pragma unroll
      for (int r = 0; r < 4; r++) mt[r] = fmaxf(mt[r], __shfl_xor(mt[r], off));

    float alpha[4], rs[4];
#pragma unroll
    for (int r = 0; r < 4; r++) {
      const float mn = fmaxf(m_i[r], mt[r]);
      alpha[r] = (mn < -1e37f) ? 1.f : __expf(m_i[r] - mn);
      m_i[r] = mn;
      rs[r] = 0.f;
    }
#pragma unroll
    for (int ns = 0; ns < 4; ns++) {
#pragma unroll
      for (int r = 0; r < 4; r++) {
        const float p = (S[ns][r] < -1e37f) ? 0.f : __expf(S[ns][r] - m_i[r]);
        rs[r] += p;
        Pw[(quad * 4 + r) * PSTR + ns * 16 + l16] = f2bf(p);
      }
    }
#pragma unroll
    for (int off = 8; off >= 1; off >>= 1)
#pragma unroll
      for (int r = 0; r < 4; r++) rs[r] += __shfl_xor(rs[r], off);
#pragma unroll
    for (int r = 0; r < 4; r++) l_i[r] = l_i[r] * alpha[r] + rs[r];
#pragma unroll
    for (int v8 = 0; v8 < 8; v8++)
#pragma unroll
      for (int r = 0; r < 4; r++) O[v8][r] *= alpha[r];

#pragma unroll
    for (int ks = 0; ks < 2; ks++) {
      short8 pf = *(const short8*)(Pw + l16 * PSTR + ks * 32 + quad * 8);
#pragma unroll
      for (int v8 = 0; v8 < 8; v8++) {
        short8 vf = *(const short8*)(Vt + (v8 * 16 + l16) * VSTR + ks * 32 + quad * 8);
        O[v8] = __builtin_amdgcn_mfma_f32_16x16x32_bf16(pf, vf, O[v8], 0, 0, 0);
      }
    }
  }

#pragma unroll
  for (int r = 0; r < 4; r++) {
    const float inv = 1.f / l_i[r];
    short* op = attn_out + (size_t)(b * TT + qg[r]) * D_MODEL + h * HEAD_DIM + l16;
#pragma unroll
    for (int v8 = 0; v8 < 8; v8++)
      op[v8 * 16] = f2bf(O[v8][r] * inv);
  }
}

// ---------------------------------------------------------------------------
extern "C" void kernel_launch(void* const* d_in, const int* in_sizes, int n_in,
                              void* d_out, int out_size, void* d_ws, size_t ws_size,
                              hipStream_t stream)
{
  const float* x     = (const float*)d_in[0];
  const float* sin_t = (const float*)d_in[1];
  const float* cos_t = (const float*)d_in[2];
  const int*   doc   = (const int*)  d_in[3];
  const float* W_qkv = (const float*)d_in[4];
  const float* W_out = (const float*)d_in[5];
  float* out = (float*)d_out;

  const int M = BB * TT;  // 4096

  char* p = (char*)d_ws;
  short* qkv_bf = (short*)p; p += (size_t)M * QKV_N * 2;
  short* xb     = (short*)p; p += (size_t)M * D_MODEL * 2;
  short* attn_bf = xb;  // alias: xb dead after GEMM1
  short* Vtb    = (short*)p; p += (size_t)BB * 128 * TT * 2;
  short* Wqkv_t = (short*)p; p += (size_t)QKV_N * D_MODEL * 2;
  short* Wout_t = (short*)p;

  convert_x<<<(M * D_MODEL / 4) / 256, 256, 0, stream>>>(x, xb);
  {
    dim3 grid(QKV_N / 32, D_MODEL / 32), blk(32, 8);
    transpose_w_bf<<<grid, blk, 0, stream>>>(W_qkv, Wqkv_t, D_MODEL, QKV_N);
  }
  {
    dim3 grid(D_MODEL / 32, D_MODEL / 32), blk(32, 8);
    transpose_w_bf<<<grid, blk, 0, stream>>>(W_out, Wout_t, D_MODEL, D_MODEL);
  }
  {
    dim3 grid(QKV_N / 128, M / 128);
    gemm_mfma_bt<true><<<grid, 256, 0, stream>>>(xb, Wqkv_t, qkv_bf, M, QKV_N, D_MODEL);
  }
  {
    const int total = BB * TT * (NUM_HEADS + 1) * 64;
    rope_bf<<<(total + 255) / 256, 256, 0, stream>>>(qkv_bf, sin_t, cos_t);
  }
  {
    dim3 grid(TT / 256, HEAD_DIM, BB);
    transpose_v<<<grid, 256, 0, stream>>>(qkv_bf, Vtb);
  }
  {
    dim3 grid(TT / 64, NUM_HEADS, BB);
    attn_mfma<<<grid, 256, 0, stream>>>(qkv_bf, Vtb, doc, attn_bf);
  }
  {
    dim3 grid(D_MODEL / 128, M / 128);
    gemm_mfma_bt<false><<<grid, 256, 0, stream>>>(attn_bf, Wout_t, out, M, D_MODEL, D_MODEL);
  }
}